// Round 11
// baseline (1516.967 us; speedup 1.0000x reference)
//
#include <hip/hip_runtime.h>
#include <hip/hip_bf16.h>

#define TT 512
#define NWGS 128       // 128 WGs x 4 batch rows
#define NTHREADS 512
#define CH 32          // steps per chunk
#define NCH 16         // 512/32
#define SLOT 576       // shorts per h slot: 4 rows x 144 (288B row stride)
#define RSTR 144

typedef float f32x4 __attribute__((ext_vector_type(4)));
typedef unsigned int uint4v __attribute__((ext_vector_type(4)));

// Raw barrier: LDS drain only; global loads stay in flight.
#define BAR() asm volatile("s_waitcnt lgkmcnt(0)\n\ts_barrier" ::: "memory")

__device__ __forceinline__ unsigned short f2bf(float f) {
  unsigned int u = __float_as_uint(f);
  u = u + 0x7FFFu + ((u >> 16) & 1u);
  return (unsigned short)(u >> 16);
}
__device__ __forceinline__ float sigm(float x) {
  return __builtin_amdgcn_rcpf(1.f + __builtin_amdgcn_exp2f(-1.44269504f * x));
}
__device__ __forceinline__ float tanh_(float x) {
  return 1.f - 2.f * __builtin_amdgcn_rcpf(1.f + __builtin_amdgcn_exp2f(2.88539008f * x));
}
__device__ __forceinline__ float softplus_(float x) {
  if (x > 15.f) return x;
  float e = __builtin_amdgcn_exp2f(1.44269504f * x);
  return 0.69314718f * __builtin_amdgcn_logf(1.f + e);
}

// Load a 16B weight fragment and pin it into an AGPR quad.
__device__ __forceinline__ uint4v pin_a(const unsigned short* p) {
  uint4v u = *(const uint4v*)p;
  asm volatile("" : "+a"(u));
  return u;
}

// MFMA, A from VGPR (activations), B from AGPR (resident weights).
__device__ __forceinline__ void mfma_va(f32x4& acc, uint4v a, uint4v b) {
  asm volatile("v_mfma_f32_16x16x32_bf16 %0, %1, %2, %0" : "+v"(acc) : "v"(a), "a"(b));
}
// Last write of an accumulator before VALU/shuffle reads: manual hazard nops.
__device__ __forceinline__ void mfma_va_end(f32x4& acc, uint4v a, uint4v b) {
  asm volatile("v_mfma_f32_16x16x32_bf16 %0, %1, %2, %0\n\ts_nop 7"
               : "+v"(acc) : "v"(a), "a"(b));
}

// Pack a [512][K] f32 weight matrix into bf16 B-fragment order:
// dst[((tau*ktiles + c)*64 + l)*8 + i] = W[tau*16 + (l&15)][c*32 + 8*(l>>4) + i]
__global__ void pack_w_kern(const float* __restrict__ src, unsigned short* __restrict__ dst,
                            int K, int ktiles) {
  int tid = blockIdx.x * 256 + threadIdx.x;
  int total = 32 * ktiles * 64;
  if (tid >= total) return;
  int l = tid & 63;
  int c = (tid >> 6) % ktiles;
  int tau = tid / (64 * ktiles);
  int n = tau * 16 + (l & 15);
  int k0 = c * 32 + 8 * (l >> 4);
  unsigned short o[8];
#pragma unroll
  for (int i = 0; i < 8; ++i) {
    int k = k0 + i;
    float v = (k < K) ? src[n * K + k] : 0.f;
    o[i] = f2bf(v);
  }
  *(uint4v*)(dst + (size_t)tid * 8) = *(const uint4v*)o;
}

// Build x0 (concat cont feats + embeddings), bf16, A-fragment order over 32
// 16-row batch tiles, K padded 22->32.
__global__ void pack_x0_kern(const float* __restrict__ xc, const int* __restrict__ idxs,
                             const int* __restrict__ idxi, const float* __restrict__ es,
                             const float* __restrict__ ei, unsigned short* __restrict__ dst) {
  int tid = blockIdx.x * 256 + threadIdx.x;
  if (tid >= TT * 32 * 64) return;
  int l = tid & 63;
  int b = (tid >> 6) & 31;
  int t = tid >> 11;
  int bi = b * 16 + (l & 15);
  int k0 = 8 * (l >> 4);
  int si = idxs[bi * TT + t];
  int it = idxi[bi * TT + t];
  const float* xr = xc + ((size_t)bi * TT + t) * 12;
  unsigned short o[8];
#pragma unroll
  for (int i = 0; i < 8; ++i) {
    int k = k0 + i;
    float v;
    if (k < 12)      v = xr[k];
    else if (k < 17) v = es[si * 5 + (k - 12)];
    else if (k < 22) v = ei[it * 5 + (k - 17)];
    else             v = 0.f;
    o[i] = f2bf(v);
  }
  *(uint4v*)(dst + (size_t)tid * 8) = *(const uint4v*)o;
}

// Gaussian head for one step; reads compact h2 slot [4][RSTR]. Wave 0 only.
// Vectorized: 2x b128 h-reads + 4x b128 weight-reads, bit-unpacked bf16.
__device__ __forceinline__ void head_step(
    int b, int t, const unsigned short* slotbase,
    const float* wmS, const float* waS, const float* vS,
    float bmv, float bav, float* out) {
  const int tid = threadIdx.x;
  if (tid >= 64) return;
  int s_ = tid & 7, hd = (tid >> 3) & 1, bi = tid >> 4;  // bi 0..3
  const float* wv = hd ? waS : wmS;
  const uint4v* hp = (const uint4v*)(slotbase + bi * RSTR + s_ * 16);
  uint4v q0 = hp[0], q1 = hp[1];
  const f32x4* wp4 = (const f32x4*)(wv + s_ * 16);
  f32x4 w0 = wp4[0], w1 = wp4[1], w2 = wp4[2], w3 = wp4[3];
  float part = 0.f;
  part += __uint_as_float(q0[0] << 16) * w0[0];
  part += __uint_as_float(q0[0] & 0xffff0000u) * w0[1];
  part += __uint_as_float(q0[1] << 16) * w0[2];
  part += __uint_as_float(q0[1] & 0xffff0000u) * w0[3];
  part += __uint_as_float(q0[2] << 16) * w1[0];
  part += __uint_as_float(q0[2] & 0xffff0000u) * w1[1];
  part += __uint_as_float(q0[3] << 16) * w1[2];
  part += __uint_as_float(q0[3] & 0xffff0000u) * w1[3];
  part += __uint_as_float(q1[0] << 16) * w2[0];
  part += __uint_as_float(q1[0] & 0xffff0000u) * w2[1];
  part += __uint_as_float(q1[1] << 16) * w2[2];
  part += __uint_as_float(q1[1] & 0xffff0000u) * w2[3];
  part += __uint_as_float(q1[2] << 16) * w3[0];
  part += __uint_as_float(q1[2] & 0xffff0000u) * w3[1];
  part += __uint_as_float(q1[3] << 16) * w3[2];
  part += __uint_as_float(q1[3] & 0xffff0000u) * w3[3];
  part += __shfl_xor(part, 1);
  part += __shfl_xor(part, 2);
  part += __shfl_xor(part, 4);
  if (s_ == 0) {
    float val = part + (hd ? bav : bmv);
    if (hd) val = softplus_(val);
    out[(((size_t)(b * 4 + bi)) * TT + t) * 2 + hd] = val * vS[bi];
  }
}

// One layer's scan over one chunk. Weights AGPR-resident; ping-pong chunk
// buffers (read inb slot tt, write outb slot tt) -> no same-slot hazards and
// no prefetch registers. One raw barrier per step.
template<int L>
__device__ __forceinline__ void scan_chunk(
    int k, int b, const unsigned short* wp_ih, const unsigned short* wp_hh,
    const unsigned short* x0p, const unsigned short* inb, unsigned short* outb,
    unsigned short* carry, float& cc, const float (&bia)[4],
    const float* wmS, const float* waS, const float* vS,
    float bmv, float bav, float* out) {
  const int tid = threadIdx.x;
  const int l = tid & 63;
  const int w = tid >> 6;
  const int j = w * 16 + (l & 15);
  const int afrag = (l & 3) * RSTR + 8 * (l >> 4);  // + c*32 per k-tile (dup rows)
  const int xlane = (l & 48) | ((b & 3) * 4 + (l & 3));
  const int r_ = l >> 4;
  const int src = l & 15;

  // -------- weight burst into AGPRs, grouped (sched_barrier caps VGPR spike) --
  uint4v ihf[4][4], hhf[4][4];
  if (L == 0) {
#pragma unroll
    for (int g = 0; g < 4; ++g)
      ihf[g][0] = pin_a(wp_ih + ((size_t)(g * 8 + w) * 64 + l) * 8);
    __builtin_amdgcn_sched_barrier(0);
  } else {
#pragma unroll
    for (int g = 0; g < 4; ++g) {
#pragma unroll
      for (int c = 0; c < 4; ++c)
        ihf[g][c] = pin_a(wp_ih + ((size_t)((g * 8 + w) * 4 + c) * 64 + l) * 8);
      __builtin_amdgcn_sched_barrier(0);
    }
  }
#pragma unroll
  for (int g = 0; g < 4; ++g) {
#pragma unroll
    for (int c = 0; c < 4; ++c)
      hhf[g][c] = pin_a(wp_hh + ((size_t)((g * 8 + w) * 4 + c) * 64 + l) * 8);
    __builtin_amdgcn_sched_barrier(0);
  }
  asm volatile("s_nop 1");  // accvgpr_write -> MFMA B-read wait states

  uint4v xcur;
  if (L == 0)
    xcur = *(const uint4v*)(x0p + (((size_t)(k * CH) * 32 + (b >> 2)) * 64 + xlane) * 8);

  for (int tt = 0; tt < CH; ++tt) {
    const int t = k * CH + tt;
    BAR();  // step tt-1 writes visible
    if (L == 2 && tt > 0)
      head_step(b, t - 1, outb + (tt - 1) * SLOT, wmS, waS, vS, bmv, bav, out);
    uint4v xnxt, inF[4], ah[4];
    if (L == 0) {
      int tn = (tt < CH - 1) ? t + 1 : t;
      xnxt = *(const uint4v*)(x0p + (((size_t)tn * 32 + (b >> 2)) * 64 + xlane) * 8);
    } else {
#pragma unroll
      for (int c = 0; c < 4; ++c)
        inF[c] = *(const uint4v*)(inb + tt * SLOT + afrag + c * 32);
    }
    const unsigned short* ahb = (tt == 0) ? carry : outb + (tt - 1) * SLOT;
#pragma unroll
    for (int c = 0; c < 4; ++c) ah[c] = *(const uint4v*)(ahb + afrag + c * 32);
    f32x4 acc[4];
#pragma unroll
    for (int g = 0; g < 4; ++g) { float bb = bia[g]; f32x4 z = {bb, bb, bb, bb}; acc[g] = z; }
    if (L == 0) {
#pragma unroll
      for (int g = 0; g < 4; ++g) mfma_va(acc[g], xcur, ihf[g][0]);
    } else {
#pragma unroll
      for (int c = 0; c < 4; ++c)
#pragma unroll
        for (int g = 0; g < 4; ++g) mfma_va(acc[g], inF[c], ihf[g][c]);
    }
#pragma unroll
    for (int c = 0; c < 4; ++c)
#pragma unroll
      for (int g = 0; g < 4; ++g) {
        if (c == 3) mfma_va_end(acc[g], ah[c], hhf[g][c]);  // +s_nop 7
        else        mfma_va(acc[g], ah[c], hhf[g][c]);
      }

    // shuffle-compact: real rows live in lanes 0-15's 4 acc slots
    float gv[4];
#pragma unroll
    for (int g = 0; g < 4; ++g) {
      float v0 = __shfl(acc[g][0], src);
      float v1 = __shfl(acc[g][1], src);
      float v2 = __shfl(acc[g][2], src);
      float v3 = __shfl(acc[g][3], src);
      float va = (r_ & 1) ? v1 : v0;
      float vb = (r_ & 1) ? v3 : v2;
      gv[g] = (r_ & 2) ? vb : va;
    }
    float ig = sigm(gv[0]);
    float fg = sigm(gv[1]);
    float gt = tanh_(gv[2]);
    float og = sigm(gv[3]);
    cc = fg * cc + ig * gt;
    float h = og * tanh_(cc);
    unsigned short hb = f2bf(h);
    outb[tt * SLOT + r_ * RSTR + j] = hb;
    if (tt == CH - 1) carry[r_ * RSTR + j] = hb;
    if (L == 0) xcur = xnxt;
  }
  if (L == 2) {
    BAR();
    head_step(b, k * CH + CH - 1, outb + (CH - 1) * SLOT, wmS, waS, vS, bmv, bav, out);
  }
}

__attribute__((amdgpu_waves_per_eu(2, 2)))  // cap 2 waves/SIMD -> 256-reg budget
__global__ void __launch_bounds__(NTHREADS)
lstm_seq4_kern(
    const unsigned short* __restrict__ wp_ih0, const unsigned short* __restrict__ wp_hh0,
    const unsigned short* __restrict__ wp_ih1, const unsigned short* __restrict__ wp_hh1,
    const unsigned short* __restrict__ wp_ih2, const unsigned short* __restrict__ wp_hh2,
    const unsigned short* __restrict__ x0p,
    const float* __restrict__ b0, const float* __restrict__ b1, const float* __restrict__ b2,
    const float* __restrict__ Wm, const float* __restrict__ bm,
    const float* __restrict__ Wa, const float* __restrict__ ba,
    const float* __restrict__ v, float* __restrict__ out) {
  __shared__ __align__(16) unsigned short bufS[2][CH * SLOT];  // ping-pong (72 KB)
  __shared__ __align__(16) unsigned short carryS[3 * SLOT];    // per-layer h carry
  __shared__ __align__(16) float wmS[128], waS[128];
  __shared__ float vS[4];

  const int tid = threadIdx.x;
  const int b = blockIdx.x;      // 0..127, batch rows [b*4, b*4+4)
  const int l = tid & 63;
  const int w = tid >> 6;
  const int j = w * 16 + (l & 15);

  for (int i = tid; i < 3 * SLOT; i += NTHREADS) carryS[i] = 0;
  if (tid < 128) { wmS[tid] = Wm[tid]; waS[tid] = Wa[tid]; }
  if (tid < 4) vS[tid] = v[b * 4 + tid];

  float bia0[4], bia1[4], bia2[4];
#pragma unroll
  for (int g = 0; g < 4; ++g) {
    bia0[g] = b0[g * 128 + j];
    bia1[g] = b1[g * 128 + j];
    bia2[g] = b2[g * 128 + j];
  }
  float cc0 = 0.f, cc1 = 0.f, cc2 = 0.f;
  const float bmv = bm[0], bav = ba[0];

  // Laundered weight base pointers: block LICM of bursts out of the chunk loop.
  size_t p_ih0 = (size_t)wp_ih0, p_hh0 = (size_t)wp_hh0;
  size_t p_ih1 = (size_t)wp_ih1, p_hh1 = (size_t)wp_hh1;
  size_t p_ih2 = (size_t)wp_ih2, p_hh2 = (size_t)wp_hh2;

  __syncthreads();

  for (int k = 0; k < NCH; ++k) {
    asm volatile("" : "+s"(p_ih0), "+s"(p_hh0), "+s"(p_ih1), "+s"(p_hh1),
                      "+s"(p_ih2), "+s"(p_hh2));
    scan_chunk<0>(k, b, (const unsigned short*)p_ih0, (const unsigned short*)p_hh0,
                  x0p, nullptr, bufS[0], carryS, cc0, bia0, wmS, waS, vS, bmv, bav, out);
    scan_chunk<1>(k, b, (const unsigned short*)p_ih1, (const unsigned short*)p_hh1,
                  x0p, bufS[0], bufS[1], carryS + SLOT, cc1, bia1,
                  wmS, waS, vS, bmv, bav, out);
    scan_chunk<2>(k, b, (const unsigned short*)p_ih2, (const unsigned short*)p_hh2,
                  x0p, bufS[1], bufS[0], carryS + 2 * SLOT, cc2, bia2,
                  wmS, waS, vS, bmv, bav, out);
  }
}

extern "C" void kernel_launch(void* const* d_in, const int* in_sizes, int n_in,
                              void* d_out, int out_size, void* d_ws, size_t ws_size,
                              hipStream_t stream) {
  const float* x_cont    = (const float*)d_in[0];
  const int*   idx_shops = (const int*)d_in[1];
  const int*   idx_items = (const int*)d_in[2];
  const float* v         = (const float*)d_in[3];
  const float* emb_shops = (const float*)d_in[4];
  const float* emb_items = (const float*)d_in[5];
  const float* Wih0 = (const float*)d_in[6];
  const float* Whh0 = (const float*)d_in[7];
  const float* b0   = (const float*)d_in[8];
  const float* Wih1 = (const float*)d_in[9];
  const float* Whh1 = (const float*)d_in[10];
  const float* b1   = (const float*)d_in[11];
  const float* Wih2 = (const float*)d_in[12];
  const float* Whh2 = (const float*)d_in[13];
  const float* b2   = (const float*)d_in[14];
  const float* Wm   = (const float*)d_in[15];
  const float* bm   = (const float*)d_in[16];
  const float* Wa   = (const float*)d_in[17];
  const float* ba   = (const float*)d_in[18];
  float* out = (float*)d_out;

  unsigned short* ws = (unsigned short*)d_ws;
  unsigned short* wp_ih0 = ws;                  // 32*1*64*8   = 16384 el
  unsigned short* wp_hh0 = wp_ih0 + 16384;      // 32*4*64*8   = 65536 el
  unsigned short* wp_ih1 = wp_hh0 + 65536;
  unsigned short* wp_hh1 = wp_ih1 + 65536;
  unsigned short* wp_ih2 = wp_hh1 + 65536;
  unsigned short* wp_hh2 = wp_ih2 + 65536;
  unsigned short* x0p    = wp_hh2 + 65536;      // 512*32*64*8 = 8388608 el (17.5 MB total)

  pack_w_kern<<<8, 256, 0, stream>>>(Wih0, wp_ih0, 22, 1);
  pack_w_kern<<<32, 256, 0, stream>>>(Whh0, wp_hh0, 128, 4);
  pack_w_kern<<<32, 256, 0, stream>>>(Wih1, wp_ih1, 128, 4);
  pack_w_kern<<<32, 256, 0, stream>>>(Whh1, wp_hh1, 128, 4);
  pack_w_kern<<<32, 256, 0, stream>>>(Wih2, wp_ih2, 128, 4);
  pack_w_kern<<<32, 256, 0, stream>>>(Whh2, wp_hh2, 128, 4);
  pack_x0_kern<<<4096, 256, 0, stream>>>(x_cont, idx_shops, idx_items,
                                         emb_shops, emb_items, x0p);
  lstm_seq4_kern<<<NWGS, NTHREADS, 0, stream>>>(wp_ih0, wp_hh0, wp_ih1, wp_hh1,
                                                wp_ih2, wp_hh2, x0p,
                                                b0, b1, b2, Wm, bm, Wa, ba, v, out);
}